// Round 3
// baseline (178.684 us; speedup 1.0000x reference)
//
#include <hip/hip_runtime.h>

// 4-stream 2-layer LSTM, H=32, T=129, IN=1.
// One block of 256 threads; wave s (=tid>>6) owns stream s end-to-end.
// Lane l owns gate rows l and l+64 (gate order i,f,g,o in blocks of 32).
// All weight rows live in VGPRs; h vectors are broadcast via v_readlane into
// SGPRs so the dot-product FMAs read h as the scalar operand. No barriers in
// the main loop (each stream is wave-local until the output heads).

#define HDIM 32
#define SEQT 129
#define NS 4

__device__ __forceinline__ float rdlane(float v, int k) {
  return __int_as_float(__builtin_amdgcn_readlane(__float_as_int(v), k));
}
__device__ __forceinline__ float fsig(float x) {
  return 1.0f / (1.0f + __expf(-x));
}

__global__ __launch_bounds__(256, 1)
void lstm4_kernel(const float* __restrict__ x,
                  const float* __restrict__ Wih0, const float* __restrict__ Whh0,
                  const float* __restrict__ bih0, const float* __restrict__ bhh0,
                  const float* __restrict__ Wih1, const float* __restrict__ Whh1,
                  const float* __restrict__ bih1, const float* __restrict__ bhh1,
                  const float* __restrict__ Wt,  const float* __restrict__ bt,
                  const float* __restrict__ Wf1, const float* __restrict__ bf1,
                  const float* __restrict__ Wf2, const float* __restrict__ bf2,
                  float* __restrict__ out) {
  const int tid = threadIdx.x;
  const int s = tid >> 6;   // stream / wave id
  const int l = tid & 63;   // lane

  __shared__ float xs[NS * SEQT];
  __shared__ float hfin[NS * HDIM];

  // stage x (S,T,1) -> LDS, one-time
  for (int i = tid; i < NS * SEQT; i += 256) xs[i] = x[i];
  __syncthreads();

  const int r1 = s * 128 + l;        // gate row 1 (i or f block)
  const int r2 = s * 128 + l + 64;   // gate row 2 (g or o block)

  // ---- load weight rows into registers (one-time) ----
  float wh0a[HDIM], wh0b[HDIM], wi1a[HDIM], wi1b[HDIM], wh1a[HDIM], wh1b[HDIM];
  #pragma unroll
  for (int k = 0; k < HDIM; k += 4) {
    float4 v;
    v = *(const float4*)(Whh0 + r1 * 32 + k);
    wh0a[k] = v.x; wh0a[k+1] = v.y; wh0a[k+2] = v.z; wh0a[k+3] = v.w;
    v = *(const float4*)(Whh0 + r2 * 32 + k);
    wh0b[k] = v.x; wh0b[k+1] = v.y; wh0b[k+2] = v.z; wh0b[k+3] = v.w;
    v = *(const float4*)(Wih1 + r1 * 32 + k);
    wi1a[k] = v.x; wi1a[k+1] = v.y; wi1a[k+2] = v.z; wi1a[k+3] = v.w;
    v = *(const float4*)(Wih1 + r2 * 32 + k);
    wi1b[k] = v.x; wi1b[k+1] = v.y; wi1b[k+2] = v.z; wi1b[k+3] = v.w;
    v = *(const float4*)(Whh1 + r1 * 32 + k);
    wh1a[k] = v.x; wh1a[k+1] = v.y; wh1a[k+2] = v.z; wh1a[k+3] = v.w;
    v = *(const float4*)(Whh1 + r2 * 32 + k);
    wh1b[k] = v.x; wh1b[k+1] = v.y; wh1b[k+2] = v.z; wh1b[k+3] = v.w;
  }
  const float wx0a = Wih0[r1];
  const float wx0b = Wih0[r2];
  const float b0a  = bih0[r1] + bhh0[r1];
  const float b0b  = bih0[r2] + bhh0[r2];
  const float b1a  = bih1[r1] + bhh1[r1];
  const float b1b  = bih1[r2] + bhh1[r2];

  // lane-constant activation fixups:
  // gate2 is g (tanh) on lanes<32, o (sigmoid) on lanes>=32.
  // tanh(x) = 2*sigmoid(2x)-1  -> a2 = fma(sigmoid(v2*m2), m2, add2)
  const bool  lo   = (l < 32);
  const float m2   = lo ? 2.0f : 1.0f;
  const float add2 = lo ? -1.0f : 0.0f;

  float h0s[HDIM], h1s[HDIM];
  #pragma unroll
  for (int k = 0; k < HDIM; ++k) { h0s[k] = 0.0f; h1s[k] = 0.0f; }
  float c0 = 0.0f, c1 = 0.0f;
  float h1new = 0.0f;

  #pragma unroll 1
  for (int t = 0; t < SEQT; ++t) {
    const float xt = xs[s * SEQT + t];

    // ---------- layer 0: gates = Whh0 @ h0 + Wih0*x + b ----------
    float p1a = b0a, p1b = 0.f, p1c = 0.f, p1d = 0.f;
    float p2a = b0b, p2b = 0.f, p2c = 0.f, p2d = 0.f;
    p1a = fmaf(wx0a, xt, p1a);
    p2a = fmaf(wx0b, xt, p2a);
    #pragma unroll
    for (int k = 0; k < HDIM; k += 4) {
      p1a = fmaf(wh0a[k],   h0s[k],   p1a);
      p1b = fmaf(wh0a[k+1], h0s[k+1], p1b);
      p1c = fmaf(wh0a[k+2], h0s[k+2], p1c);
      p1d = fmaf(wh0a[k+3], h0s[k+3], p1d);
      p2a = fmaf(wh0b[k],   h0s[k],   p2a);
      p2b = fmaf(wh0b[k+1], h0s[k+1], p2b);
      p2c = fmaf(wh0b[k+2], h0s[k+2], p2c);
      p2d = fmaf(wh0b[k+3], h0s[k+3], p2d);
    }
    const float v1 = (p1a + p1b) + (p1c + p1d);
    const float v2 = (p2a + p2b) + (p2c + p2d);

    const float a1  = fsig(v1);                 // sigmoid(i) / sigmoid(f)
    const float sv2 = fsig(v2 * m2);
    const float a2  = fmaf(sv2, m2, add2);      // tanh(g) / sigmoid(o)
    const float p   = a1 * a2;                  // i*g on lanes<32
    const float swf = __shfl_xor(a1, 32);       // lanes<32 get sigmoid(f)
    const float swo = __shfl_xor(a2, 32);       // lanes<32 get sigmoid(o)
    c0 = fmaf(swf, c0, p);
    const float th0 = fmaf(fsig(2.0f * c0), 2.0f, -1.0f);  // tanh(c0)
    const float h0new = swo * th0;              // valid on lanes<32

    #pragma unroll
    for (int k = 0; k < HDIM; ++k) h0s[k] = rdlane(h0new, k);

    // ---------- layer 1: gates = Wih1 @ h0new + Whh1 @ h1 + b ----------
    float q1a = b1a, q1b = 0.f, q1c = 0.f, q1d = 0.f;
    float q2a = b1b, q2b = 0.f, q2c = 0.f, q2d = 0.f;
    #pragma unroll
    for (int k = 0; k < HDIM; k += 4) {
      q1a = fmaf(wi1a[k],   h0s[k],   q1a);
      q1b = fmaf(wi1a[k+1], h0s[k+1], q1b);
      q1c = fmaf(wi1a[k+2], h0s[k+2], q1c);
      q1d = fmaf(wi1a[k+3], h0s[k+3], q1d);
      q2a = fmaf(wi1b[k],   h0s[k],   q2a);
      q2b = fmaf(wi1b[k+1], h0s[k+1], q2b);
      q2c = fmaf(wi1b[k+2], h0s[k+2], q2c);
      q2d = fmaf(wi1b[k+3], h0s[k+3], q2d);
      q1a = fmaf(wh1a[k],   h1s[k],   q1a);
      q1b = fmaf(wh1a[k+1], h1s[k+1], q1b);
      q1c = fmaf(wh1a[k+2], h1s[k+2], q1c);
      q1d = fmaf(wh1a[k+3], h1s[k+3], q1d);
      q2a = fmaf(wh1b[k],   h1s[k],   q2a);
      q2b = fmaf(wh1b[k+1], h1s[k+1], q2b);
      q2c = fmaf(wh1b[k+2], h1s[k+2], q2c);
      q2d = fmaf(wh1b[k+3], h1s[k+3], q2d);
    }
    const float w1 = (q1a + q1b) + (q1c + q1d);
    const float w2 = (q2a + q2b) + (q2c + q2d);

    const float A1  = fsig(w1);
    const float sw2 = fsig(w2 * m2);
    const float A2  = fmaf(sw2, m2, add2);
    const float P   = A1 * A2;
    const float SWF = __shfl_xor(A1, 32);
    const float SWO = __shfl_xor(A2, 32);
    c1 = fmaf(SWF, c1, P);
    const float th1 = fmaf(fsig(2.0f * c1), 2.0f, -1.0f);
    h1new = SWO * th1;

    #pragma unroll
    for (int k = 0; k < HDIM; ++k) h1s[k] = rdlane(h1new, k);
  }

  // ---------- output heads ----------
  if (l < HDIM) hfin[s * HDIM + l] = h1new;
  __syncthreads();

  float acc = 0.0f;
  if (s == 0) {
    // targetOut = Wt . concat(h1 streams 0..3) + bt   (128 terms, 2 per lane)
    acc = fmaf(Wt[l], hfin[l], Wt[l + 64] * hfin[l + 64]);
  } else {
    const float* Wf = (s == 1) ? Wf1 : Wf2;  // f3 reuses Wf2/bf2 (reference bug kept)
    if (l < HDIM) acc = Wf[l] * hfin[s * HDIM + l];
  }
  #pragma unroll
  for (int off = 32; off > 0; off >>= 1) acc += __shfl_xor(acc, off);
  if (l == 0) {
    const float bias = (s == 0) ? bt[0] : ((s == 1) ? bf1[0] : bf2[0]);
    out[s] = acc + bias;
  }
}

extern "C" void kernel_launch(void* const* d_in, const int* in_sizes, int n_in,
                              void* d_out, int out_size, void* d_ws, size_t ws_size,
                              hipStream_t stream) {
  const float* x    = (const float*)d_in[0];
  const float* Wih0 = (const float*)d_in[1];
  const float* Whh0 = (const float*)d_in[2];
  const float* bih0 = (const float*)d_in[3];
  const float* bhh0 = (const float*)d_in[4];
  const float* Wih1 = (const float*)d_in[5];
  const float* Whh1 = (const float*)d_in[6];
  const float* bih1 = (const float*)d_in[7];
  const float* bhh1 = (const float*)d_in[8];
  const float* Wt   = (const float*)d_in[9];
  const float* bt   = (const float*)d_in[10];
  const float* Wf1  = (const float*)d_in[11];
  const float* bf1  = (const float*)d_in[12];
  const float* Wf2  = (const float*)d_in[13];
  const float* bf2  = (const float*)d_in[14];
  float* out = (float*)d_out;

  lstm4_kernel<<<1, 256, 0, stream>>>(x, Wih0, Whh0, bih0, bhh0,
                                      Wih1, Whh1, bih1, bhh1,
                                      Wt, bt, Wf1, bf1, Wf2, bf2, out);
}

// Round 6
// 176.217 us; speedup vs baseline: 1.0140x; 1.0140x over previous
//
#include <hip/hip_runtime.h>

// 4-stream 2-layer LSTM, H=32, T=129, IN=1.
// One block of 256 threads; wave s (=tid>>6) owns stream s end-to-end.
// Lane l owns gate rows l and l+64 (gate order i,f,g,o in blocks of 32).
// R6 = R5 with pins applied to PLAIN float array elements (HIP float4's
// .x/.y/.z/.w can't bind as asm lvalues -> previous compile errors).
// Rationale (R3 evidence): VGPR_Count=144 < 192 weight floats => LLVM was
// rematerializing weight loads every step (~1000 cyc/step of vmcnt waits).

#define HDIM 32
#define SEQT 129
#define NS 4

__device__ __forceinline__ float rdlane(float v, int k) {
  return __int_as_float(__builtin_amdgcn_readlane(__float_as_int(v), k));
}
__device__ __forceinline__ float fsig(float x) {
  return 1.0f / (1.0f + __expf(-x));
}
// lanes<32 receive v[lane+32]; lanes>=32 keep their own value (high-lane
// state is dead in this kernel - only lanes 0..31 are ever read back).
__device__ __forceinline__ float swap_hi(float v) {
  auto r = __builtin_amdgcn_permlane32_swap(__float_as_int(v), __float_as_int(v),
                                            false, false);
  return __int_as_float(r[1]);
}
#define PINF(w) asm volatile("" : "+v"(w))

__global__ __launch_bounds__(256, 1)
void lstm4_kernel(const float* __restrict__ x,
                  const float* __restrict__ Wih0, const float* __restrict__ Whh0,
                  const float* __restrict__ bih0, const float* __restrict__ bhh0,
                  const float* __restrict__ Wih1, const float* __restrict__ Whh1,
                  const float* __restrict__ bih1, const float* __restrict__ bhh1,
                  const float* __restrict__ Wt,  const float* __restrict__ bt,
                  const float* __restrict__ Wf1, const float* __restrict__ bf1,
                  const float* __restrict__ Wf2, const float* __restrict__ bf2,
                  float* __restrict__ out) {
  const int tid = threadIdx.x;
  const int s = tid >> 6;   // stream / wave id
  const int l = tid & 63;   // lane

  __shared__ float xs[NS * SEQT + 1];
  __shared__ float hfin[NS * HDIM];

  // stage x (S,T,1) -> LDS, one-time
  for (int i = tid; i < NS * SEQT; i += 256) xs[i] = x[i];
  if (tid == 0) xs[NS * SEQT] = 0.0f;  // prefetch pad
  __syncthreads();

  const int r1 = s * 128 + l;        // gate row 1 (i or f block)
  const int r2 = s * 128 + l + 64;   // gate row 2 (g or o block)

  // ---- load weight rows into registers (one-time), then PIN them ----
  float wh0a[HDIM], wh0b[HDIM], wi1a[HDIM], wi1b[HDIM], wh1a[HDIM], wh1b[HDIM];
  #pragma unroll
  for (int j = 0; j < 8; ++j) {
    float4 v;
    v = *(const float4*)(Whh0 + r1 * 32 + 4 * j);
    wh0a[4*j] = v.x; wh0a[4*j+1] = v.y; wh0a[4*j+2] = v.z; wh0a[4*j+3] = v.w;
    v = *(const float4*)(Whh0 + r2 * 32 + 4 * j);
    wh0b[4*j] = v.x; wh0b[4*j+1] = v.y; wh0b[4*j+2] = v.z; wh0b[4*j+3] = v.w;
    v = *(const float4*)(Wih1 + r1 * 32 + 4 * j);
    wi1a[4*j] = v.x; wi1a[4*j+1] = v.y; wi1a[4*j+2] = v.z; wi1a[4*j+3] = v.w;
    v = *(const float4*)(Wih1 + r2 * 32 + 4 * j);
    wi1b[4*j] = v.x; wi1b[4*j+1] = v.y; wi1b[4*j+2] = v.z; wi1b[4*j+3] = v.w;
    v = *(const float4*)(Whh1 + r1 * 32 + 4 * j);
    wh1a[4*j] = v.x; wh1a[4*j+1] = v.y; wh1a[4*j+2] = v.z; wh1a[4*j+3] = v.w;
    v = *(const float4*)(Whh1 + r2 * 32 + 4 * j);
    wh1b[4*j] = v.x; wh1b[4*j+1] = v.y; wh1b[4*j+2] = v.z; wh1b[4*j+3] = v.w;
  }
  #pragma unroll
  for (int k = 0; k < HDIM; ++k) {
    PINF(wh0a[k]); PINF(wh0b[k]);
    PINF(wi1a[k]); PINF(wi1b[k]);
    PINF(wh1a[k]); PINF(wh1b[k]);
  }
  const float wx0a = Wih0[r1];
  const float wx0b = Wih0[r2];
  const float b0a  = bih0[r1] + bhh0[r1];
  const float b0b  = bih0[r2] + bhh0[r2];
  const float b1a  = bih1[r1] + bhh1[r1];
  const float b1b  = bih1[r2] + bhh1[r2];

  // gate2 is g (tanh) on lanes<32, o (sigmoid) on lanes>=32.
  // tanh(x) = 2*sigmoid(2x)-1  -> a2 = fma(sigmoid(v2*m2), m2, add2)
  const bool  lo   = (l < 32);
  const float m2   = lo ? 2.0f : 1.0f;
  const float add2 = lo ? -1.0f : 0.0f;

  float h0s[HDIM], h1s[HDIM];
  #pragma unroll
  for (int k = 0; k < HDIM; ++k) { h0s[k] = 0.0f; h1s[k] = 0.0f; }
  float c0 = 0.0f, c1 = 0.0f;
  float h1new = 0.0f;

  float xt = xs[s * SEQT];

  #pragma unroll 1
  for (int t = 0; t < SEQT; ++t) {
    const float xt_next = xs[s * SEQT + t + 1];  // prefetch (pad covers t=128)

    // ---------- layer 0: gates = Whh0 @ h0 + Wih0*x + b ----------
    float p1a = b0a, p1b = 0.f, p1c = 0.f, p1d = 0.f;
    float p2a = b0b, p2b = 0.f, p2c = 0.f, p2d = 0.f;
    p1a = fmaf(wx0a, xt, p1a);
    p2a = fmaf(wx0b, xt, p2a);
    #pragma unroll
    for (int j = 0; j < 8; ++j) {
      p1a = fmaf(wh0a[4*j+0], h0s[4*j+0], p1a);
      p1b = fmaf(wh0a[4*j+1], h0s[4*j+1], p1b);
      p1c = fmaf(wh0a[4*j+2], h0s[4*j+2], p1c);
      p1d = fmaf(wh0a[4*j+3], h0s[4*j+3], p1d);
      p2a = fmaf(wh0b[4*j+0], h0s[4*j+0], p2a);
      p2b = fmaf(wh0b[4*j+1], h0s[4*j+1], p2b);
      p2c = fmaf(wh0b[4*j+2], h0s[4*j+2], p2c);
      p2d = fmaf(wh0b[4*j+3], h0s[4*j+3], p2d);
    }
    const float v1 = (p1a + p1b) + (p1c + p1d);
    const float v2 = (p2a + p2b) + (p2c + p2d);

    const float a1  = fsig(v1);                 // sigmoid(i) / sigmoid(f)
    const float sv2 = fsig(v2 * m2);
    const float a2  = fmaf(sv2, m2, add2);      // tanh(g) / sigmoid(o)
    const float p   = a1 * a2;                  // i*g on lanes<32
    const float swf = swap_hi(a1);              // lanes<32 get sigmoid(f)
    const float swo = swap_hi(a2);              // lanes<32 get sigmoid(o)
    c0 = fmaf(swf, c0, p);
    const float th0 = fmaf(fsig(2.0f * c0), 2.0f, -1.0f);  // tanh(c0)
    const float h0new = swo * th0;              // valid on lanes<32

    #pragma unroll
    for (int k = 0; k < HDIM; ++k) h0s[k] = rdlane(h0new, k);

    // ---------- layer 1: gates = Whh1 @ h1 + Wih1 @ h0new + b ----------
    float q1a = b1a, q1b = 0.f, q1c = 0.f, q1d = 0.f;
    float q2a = b1b, q2b = 0.f, q2c = 0.f, q2d = 0.f;
    #pragma unroll
    for (int j = 0; j < 8; ++j) {           // Whh1 part first: only needs h1(t-1)
      q1a = fmaf(wh1a[4*j+0], h1s[4*j+0], q1a);
      q1b = fmaf(wh1a[4*j+1], h1s[4*j+1], q1b);
      q1c = fmaf(wh1a[4*j+2], h1s[4*j+2], q1c);
      q1d = fmaf(wh1a[4*j+3], h1s[4*j+3], q1d);
      q2a = fmaf(wh1b[4*j+0], h1s[4*j+0], q2a);
      q2b = fmaf(wh1b[4*j+1], h1s[4*j+1], q2b);
      q2c = fmaf(wh1b[4*j+2], h1s[4*j+2], q2c);
      q2d = fmaf(wh1b[4*j+3], h1s[4*j+3], q2d);
    }
    #pragma unroll
    for (int j = 0; j < 8; ++j) {
      q1a = fmaf(wi1a[4*j+0], h0s[4*j+0], q1a);
      q1b = fmaf(wi1a[4*j+1], h0s[4*j+1], q1b);
      q1c = fmaf(wi1a[4*j+2], h0s[4*j+2], q1c);
      q1d = fmaf(wi1a[4*j+3], h0s[4*j+3], q1d);
      q2a = fmaf(wi1b[4*j+0], h0s[4*j+0], q2a);
      q2b = fmaf(wi1b[4*j+1], h0s[4*j+1], q2b);
      q2c = fmaf(wi1b[4*j+2], h0s[4*j+2], q2c);
      q2d = fmaf(wi1b[4*j+3], h0s[4*j+3], q2d);
    }
    const float w1 = (q1a + q1b) + (q1c + q1d);
    const float w2 = (q2a + q2b) + (q2c + q2d);

    const float A1  = fsig(w1);
    const float sw2 = fsig(w2 * m2);
    const float A2  = fmaf(sw2, m2, add2);
    const float P   = A1 * A2;
    const float SWF = swap_hi(A1);
    const float SWO = swap_hi(A2);
    c1 = fmaf(SWF, c1, P);
    const float th1 = fmaf(fsig(2.0f * c1), 2.0f, -1.0f);
    h1new = SWO * th1;

    #pragma unroll
    for (int k = 0; k < HDIM; ++k) h1s[k] = rdlane(h1new, k);

    xt = xt_next;
  }

  // ---------- output heads ----------
  if (l < HDIM) hfin[s * HDIM + l] = h1new;
  __syncthreads();

  float acc = 0.0f;
  if (s == 0) {
    // targetOut = Wt . concat(h1 streams 0..3) + bt   (128 terms, 2 per lane)
    acc = fmaf(Wt[l], hfin[l], Wt[l + 64] * hfin[l + 64]);
  } else {
    const float* Wf = (s == 1) ? Wf1 : Wf2;  // f3 reuses Wf2/bf2 (reference bug kept)
    if (l < HDIM) acc = Wf[l] * hfin[s * HDIM + l];
  }
  #pragma unroll
  for (int off = 32; off > 0; off >>= 1) acc += __shfl_xor(acc, off);
  if (l == 0) {
    const float bias = (s == 0) ? bt[0] : ((s == 1) ? bf1[0] : bf2[0]);
    out[s] = acc + bias;
  }
}

extern "C" void kernel_launch(void* const* d_in, const int* in_sizes, int n_in,
                              void* d_out, int out_size, void* d_ws, size_t ws_size,
                              hipStream_t stream) {
  const float* x    = (const float*)d_in[0];
  const float* Wih0 = (const float*)d_in[1];
  const float* Whh0 = (const float*)d_in[2];
  const float* bih0 = (const float*)d_in[3];
  const float* bhh0 = (const float*)d_in[4];
  const float* Wih1 = (const float*)d_in[5];
  const float* Whh1 = (const float*)d_in[6];
  const float* bih1 = (const float*)d_in[7];
  const float* bhh1 = (const float*)d_in[8];
  const float* Wt   = (const float*)d_in[9];
  const float* bt   = (const float*)d_in[10];
  const float* Wf1  = (const float*)d_in[11];
  const float* bf1  = (const float*)d_in[12];
  const float* Wf2  = (const float*)d_in[13];
  const float* bf2  = (const float*)d_in[14];
  float* out = (float*)d_out;

  lstm4_kernel<<<1, 256, 0, stream>>>(x, Wih0, Whh0, bih0, bhh0,
                                      Wih1, Whh1, bih1, bhh1,
                                      Wt, bt, Wf1, bf1, Wf2, bf2, out);
}